// Round 20
// baseline (3718.711 us; speedup 1.0000x reference)
//
#include <hip/hip_runtime.h>
#include <math.h>

#define BATCH 32
#define TLEN  512
#define HID   1024
#define G2    2048   // 2*H
#define BHID (BATCH * HID)

typedef _Float16 half8 __attribute__((ext_vector_type(8)));
typedef float f32x4 __attribute__((ext_vector_type(4)));

// fast device math: v_exp_f32 / v_rcp_f32 (ulp-level, fine vs fp16 threshold)
#define LOG2E 1.44269504f
__device__ __forceinline__ float fast_sigmoid(float z) {
    return __builtin_amdgcn_rcpf(1.f + __builtin_amdgcn_exp2f(-LOG2E * z));
}
__device__ __forceinline__ float fast_tanh(float a) {
    return 1.f - 2.f * __builtin_amdgcn_rcpf(
        1.f + __builtin_amdgcn_exp2f(2.f * LOG2E * a));
}

// ---------------------------------------------------------------------------
// fp32 -> fp16 conversion (8 elems/thread)
// ---------------------------------------------------------------------------
__global__ __launch_bounds__(256)
void conv_f16(const float* __restrict__ s, _Float16* __restrict__ d, int n8) {
    int i = blockIdx.x * 256 + threadIdx.x;
    if (i < n8) {
        int base = i * 8;
        float4 v0 = *(const float4*)&s[base];
        float4 v1 = *(const float4*)&s[base + 4];
        half8 h;
        h[0] = (_Float16)v0.x; h[1] = (_Float16)v0.y;
        h[2] = (_Float16)v0.z; h[3] = (_Float16)v0.w;
        h[4] = (_Float16)v1.x; h[5] = (_Float16)v1.y;
        h[6] = (_Float16)v1.z; h[7] = (_Float16)v1.w;
        *(half8*)&d[base] = h;
    }
}

// ---------------------------------------------------------------------------
// MFMA projection GEMM (proven R11-R19): Cw[t][b][n] = sum_k A[m][k]*W[n][k],
// m = b*T + t. fp16 in, fp16 out.
// ---------------------------------------------------------------------------
__global__ __launch_bounds__(256)
void proj_gemm_f16(const _Float16* __restrict__ A, const _Float16* __restrict__ W,
                   _Float16* __restrict__ Cw, int K) {
    const int tid = threadIdx.x;
    const int wv = tid >> 6;
    const int l  = tid & 63;
    const int m0 = blockIdx.x * 128 + (wv >> 1) * 64;
    const int n0 = blockIdx.y * 128 + (wv & 1) * 64;
    const int fr = l & 15;
    const int kg = l >> 4;

    f32x4 acc[4][4];
    #pragma unroll
    for (int i = 0; i < 4; ++i)
        #pragma unroll
        for (int j = 0; j < 4; ++j) acc[i][j] = (f32x4){0.f, 0.f, 0.f, 0.f};

    const int nkc = K >> 5;
    #pragma unroll 2
    for (int kc = 0; kc < nkc; ++kc) {
        int k = kc * 32 + kg * 8;
        half8 af[4], bf[4];
        #pragma unroll
        for (int i = 0; i < 4; ++i)
            af[i] = *(const half8*)&A[(size_t)(m0 + i * 16 + fr) * K + k];
        #pragma unroll
        for (int j = 0; j < 4; ++j)
            bf[j] = *(const half8*)&W[(size_t)(n0 + j * 16 + fr) * K + k];
        #pragma unroll
        for (int i = 0; i < 4; ++i)
            #pragma unroll
            for (int j = 0; j < 4; ++j)
                acc[i][j] = __builtin_amdgcn_mfma_f32_16x16x32_f16(
                    af[i], bf[j], acc[i][j], 0, 0, 0);
    }

    #pragma unroll
    for (int i = 0; i < 4; ++i) {
        #pragma unroll
        for (int r = 0; r < 4; ++r) {
            int m = m0 + i * 16 + (l >> 4) * 4 + r;
            int t = m & (TLEN - 1);
            int b = m >> 9;
            _Float16* dst = &Cw[((size_t)t * BATCH + b) * G2];
            #pragma unroll
            for (int j = 0; j < 4; ++j)
                dst[n0 + j * 16 + (l & 15)] = (_Float16)acc[i][j][r];
        }
    }
}

// ---------------------------------------------------------------------------
// Agent-scope (device-coherent) helpers: sc0 sc1, bypass L1/per-XCD L2.
// ---------------------------------------------------------------------------
__device__ __forceinline__ void st_flag(int* p, int v) {
    __hip_atomic_store(p, v, __ATOMIC_RELAXED, __HIP_MEMORY_SCOPE_AGENT);
}
__device__ __forceinline__ int ld_flag(const int* p) {
    return __hip_atomic_load(p, __ATOMIC_RELAXED, __HIP_MEMORY_SCOPE_AGENT);
}
__device__ __forceinline__ unsigned long long ld_h2u(const unsigned short* p) {
    return __hip_atomic_load((const unsigned long long*)p, __ATOMIC_RELAXED,
                             __HIP_MEMORY_SCOPE_AGENT);
}
__device__ __forceinline__ void st_h32(unsigned int* p, unsigned int v) {
    __hip_atomic_store(p, v, __ATOMIC_RELAXED, __HIP_MEMORY_SCOPE_AGENT);
}

#define NWG 128      // 4 batch-groups x 32 j-blocks
#define FSTRIDE 16   // flags 64 B apart
#define BT 8         // batches per WG
#define JT 32        // a-rows per WG (plus JT z-rows)

__global__ void rec_init(unsigned short* h0, int* flags) {
    int i = blockIdx.x * 256 + threadIdx.x;
    if (i < BHID) h0[i] = 0;              // fp16 +0.0
    if (i < NWG * FSTRIDE) flags[i] = 0;
}

// ---------------------------------------------------------------------------
// MFMA recurrence -- R17/R19 structure with HALVED PRODUCER FAN-IN:
// 128 WGs x 512 thr (8 waves); bt = wg&3 (4 sync groups x 32 WGs); WG owns
// 32 j-rows (a+z = 64 M-rows = 4 16-row tiles) x 8 batches; wave wv =
// K-chunks wv*4..wv*4+3, computing ALL 4 M-tiles against each shared B-frag
// (A-frags 16xhalf8 = 64 VGPR; B reused 4x). C partials through
// red[8][64][20] LDS (40 KB, padded). Gates on tid<256 (4 waves).
// Sync identical to R17/R19: poll = 32 flags (tid<32) + raw s_barrier;
// barrier B (syncthreads); h-publish + barrier C drain + per-WG flag;
// out/act store deferred after the flag. 3-ring unchanged.
// Rationale: step time is dominated by max-skew over the producer set;
// 32 producers instead of 64 shrinks the max-of-N jitter term, and each
// exchanged h-byte now feeds 2x the MFMA work.
// ---------------------------------------------------------------------------
__global__ __launch_bounds__(512, 1)
void ligru_rec(const _Float16* __restrict__ w16,   // [T][B][2H] fp16
               const _Float16* __restrict__ U16,   // [2H][H] fp16
               unsigned short* __restrict__ hring, // [3][B][H] fp16 ring
               int* __restrict__ flags,            // NWG*FSTRIDE, pre-zeroed
               float* __restrict__ out32,          // [B][T][H] fp32 (layer 1)
               _Float16* __restrict__ act16,       // [B][T][H] fp16 (layer 0)
               float* __restrict__ hlast) {        // [B][H] fp32
    __shared__ float red[8][64][20];               // wave C partials (40 KB)

    const int wg  = blockIdx.x;
    const int tid = threadIdx.x;
    const int bt  = wg & 3;
    const int jb  = wg >> 2;          // 0..31
    const int j0  = jb * JT;
    const int bg0 = bt * BT;

    const int wv   = tid >> 6;        // wave 0..7: K-chunks wv*4..wv*4+3
    const int l    = tid & 63;
    const int mrow = l & 15;          // A-frag M row within tile
    const int kg   = l >> 4;          // k-group (8 halves)
    const int bcol = bg0 + (l & 7);   // B-frag batch (cols 8-15 duplicate)

    // ---- A frags: 4 M-tiles (a0,a1,z0,z1) x 4 k-chunks = 16 half8 (64 VGPR)
    half8 Aa0[4], Aa1[4], Az0[4], Az1[4];
    #pragma unroll
    for (int kc = 0; kc < 4; ++kc) {
        int k0 = (wv * 4 + kc) * 32 + kg * 8;
        Aa0[kc] = *(const half8*)&U16[(size_t)(j0 + mrow) * HID + k0];
        Aa1[kc] = *(const half8*)&U16[(size_t)(j0 + 16 + mrow) * HID + k0];
        Az0[kc] = *(const half8*)&U16[(size_t)(HID + j0 + mrow) * HID + k0];
        Az1[kc] = *(const half8*)&U16[(size_t)(HID + j0 + 16 + mrow) * HID + k0];
    }

    unsigned short* h_t = hring;
    unsigned short* h_n = hring + BHID;
    unsigned short* h_p = hring + 2 * BHID;

    // gate coords (tid < 256): jl = row 0..31, bl = batch 0..7
    const int jl = tid & 31;
    const int bl = tid >> 5;
    const int bg = bg0 + (bl & 7);
    float hprev = 0.f;

    for (int t = 0; t < TLEN; ++t) {
        // ---- w prefetch (fp16, gate threads; issued before the poll)
        float wa = 0.f, wz = 0.f;
        if (tid < 256) {
            const _Float16* wt = &w16[((size_t)t * BATCH + bg) * G2];
            wa = (float)wt[j0 + jl];
            wz = (float)wt[HID + j0 + jl];
        }

        // ---- wait for the 32 group peers to have published h(t)
        if (t > 0) {
            if (tid < 32) {
                const int* fp = &flags[((tid << 2) + bt) * FSTRIDE];
                while (ld_flag(fp) < t)
                    __builtin_amdgcn_s_sleep(1);
            }
            __builtin_amdgcn_s_barrier();   // execution-only (R19)
        }

        // ---- B frags from coherent ring + MFMA (4 kc x 4 tiles per wave)
        f32x4 ca0 = {0.f, 0.f, 0.f, 0.f};
        f32x4 ca1 = {0.f, 0.f, 0.f, 0.f};
        f32x4 cz0 = {0.f, 0.f, 0.f, 0.f};
        f32x4 cz1 = {0.f, 0.f, 0.f, 0.f};
        #pragma unroll
        for (int kc = 0; kc < 4; ++kc) {
            int k0 = (wv * 4 + kc) * 32 + kg * 8;
            const unsigned short* hp = &h_t[(size_t)bcol * HID + k0];
            union { unsigned long long u[2]; half8 h; } B;
            B.u[0] = ld_h2u(hp);
            B.u[1] = ld_h2u(hp + 4);
            ca0 = __builtin_amdgcn_mfma_f32_16x16x32_f16(Aa0[kc], B.h, ca0, 0, 0, 0);
            ca1 = __builtin_amdgcn_mfma_f32_16x16x32_f16(Aa1[kc], B.h, ca1, 0, 0, 0);
            cz0 = __builtin_amdgcn_mfma_f32_16x16x32_f16(Az0[kc], B.h, cz0, 0, 0, 0);
            cz1 = __builtin_amdgcn_mfma_f32_16x16x32_f16(Az1[kc], B.h, cz1, 0, 0, 0);
        }

        // ---- C layout: col = l&15 (batch), row = kg*4 + r (j within tile)
        #pragma unroll
        for (int r = 0; r < 4; ++r) {
            red[wv][kg * 4 + r][l & 15]      = ca0[r];   // a rows 0-15
            red[wv][16 + kg * 4 + r][l & 15] = ca1[r];   // a rows 16-31
            red[wv][32 + kg * 4 + r][l & 15] = cz0[r];   // z rows 0-15
            red[wv][48 + kg * 4 + r][l & 15] = cz1[r];   // z rows 16-31
        }
        __syncthreads();   // barrier B: partials complete (LDS visibility)

        // ---- gates + state update (256 threads)
        unsigned int pk = 0;
        float hnew = 0.f;
        if (tid < 256) {
            float sa = 0.f, sz = 0.f;
            #pragma unroll
            for (int v = 0; v < 8; ++v) {
                sa += red[v][jl][bl];
                sz += red[v][32 + jl][bl];
            }
            float at = wa + sa;
            float zt = fast_sigmoid(wz + sz);
            float hc = fast_tanh(at);
            hnew = zt * hprev + (1.f - zt) * hc;
            hprev = hnew;

            unsigned short h16 =
                __builtin_bit_cast(unsigned short, (_Float16)hnew);
            unsigned int other = __shfl_xor((unsigned int)h16, 1);
            pk = ((jl & 1) == 0)
                ? ((unsigned int)h16 | (other << 16))
                : ((other) | ((unsigned int)h16 << 16));

            // h publish ONLY (keeps the pre-flag drain minimal)
            if (t < TLEN - 1) {
                if ((jl & 1) == 0)
                    st_h32((unsigned int*)&h_n[(size_t)bg * HID + j0 + jl], pk);
            } else {
                hlast[(size_t)bg * HID + j0 + jl] = hnew;
            }
        }

        // ---- publish barrier + flag, THEN the layer output store
        if (t < TLEN - 1) {
            __syncthreads();   // barrier C: drains vmcnt -> h stores at LLC
            if (tid == 0) st_flag(&flags[wg * FSTRIDE], t + 1);
        }
        if (tid < 256) {
            if (act16) {
                if ((jl & 1) == 0)
                    *(unsigned int*)&act16[((size_t)bg * TLEN + t) * HID
                                           + j0 + jl] = pk;
            } else {
                out32[((size_t)bg * TLEN + t) * HID + j0 + jl] = hnew;
            }
        }

        unsigned short* tmp = h_t; h_t = h_n; h_n = h_p; h_p = tmp;
    }
}

// ---------------------------------------------------------------------------
extern "C" void kernel_launch(void* const* d_in, const int* in_sizes, int n_in,
                              void* d_out, int out_size, void* d_ws, size_t ws_size,
                              hipStream_t stream) {
    (void)in_sizes; (void)n_in; (void)out_size; (void)ws_size;

    const float* x  = (const float*)d_in[0];
    const float* W0 = (const float*)d_in[1];
    const float* U0 = (const float*)d_in[2];
    const float* W1 = (const float*)d_in[3];
    const float* U1 = (const float*)d_in[4];

    float* out    = (float*)d_out;                              // [B,T,H]
    float* hstack = out + (size_t)BATCH * TLEN * HID;           // [2,B,H]

    // workspace layout
    int*            flags = (int*)d_ws;                               // 8 KB
    unsigned short* hring = (unsigned short*)(flags + NWG * FSTRIDE); // 192 KB
    _Float16*       W16   = (_Float16*)(hring + 3 * BHID);            // 4 MB
    _Float16*       U16   = W16 + (size_t)G2 * HID;                   // 4 MB
    _Float16*       xact  = U16 + (size_t)G2 * HID;                   // 32 MB
    _Float16*       wbuf  = xact + (size_t)BATCH * TLEN * HID;        // 64 MB

    dim3 gg(16384 / 128, 2048 / 128);
    int init_blocks = (BHID + 255) / 256;

    // ---- layer 0 ----
    conv_f16<<<(BATCH * TLEN * 512 / 8 + 255) / 256, 256, 0, stream>>>(
        x, xact, BATCH * TLEN * 512 / 8);
    conv_f16<<<(G2 * 512 / 8 + 255) / 256, 256, 0, stream>>>(
        W0, W16, G2 * 512 / 8);
    conv_f16<<<(G2 * HID / 8 + 255) / 256, 256, 0, stream>>>(
        U0, U16, G2 * HID / 8);
    proj_gemm_f16<<<gg, 256, 0, stream>>>(xact, W16, wbuf, 512);
    rec_init<<<init_blocks, 256, 0, stream>>>(hring, flags);
    ligru_rec<<<dim3(NWG), dim3(512), 0, stream>>>(
        wbuf, U16, hring, flags, nullptr, xact, hstack);  // fp16 act out

    // ---- layer 1 ----
    conv_f16<<<(G2 * HID / 8 + 255) / 256, 256, 0, stream>>>(
        W1, W16, G2 * HID / 8);
    conv_f16<<<(G2 * HID / 8 + 255) / 256, 256, 0, stream>>>(
        U1, U16, G2 * HID / 8);
    proj_gemm_f16<<<gg, 256, 0, stream>>>(xact, W16, wbuf, 1024);
    rec_init<<<init_blocks, 256, 0, stream>>>(hring, flags);
    ligru_rec<<<dim3(NWG), dim3(512), 0, stream>>>(
        wbuf, U16, hring, flags, out, nullptr, hstack + BHID);
}

// Round 21
// 2797.817 us; speedup vs baseline: 1.3291x; 1.3291x over previous
//
#include <hip/hip_runtime.h>
#include <math.h>

#define BATCH 32
#define TLEN  512
#define HID   1024
#define G2    2048   // 2*H
#define BHID (BATCH * HID)

typedef _Float16 half8 __attribute__((ext_vector_type(8)));
typedef float f32x4 __attribute__((ext_vector_type(4)));

#define LOG2E 1.44269504f
__device__ __forceinline__ float fast_sigmoid(float z) {
    return __builtin_amdgcn_rcpf(1.f + __builtin_amdgcn_exp2f(-LOG2E * z));
}
__device__ __forceinline__ float fast_tanh(float a) {
    return 1.f - 2.f * __builtin_amdgcn_rcpf(
        1.f + __builtin_amdgcn_exp2f(2.f * LOG2E * a));
}

// ---------------------------------------------------------------------------
// fp32 -> fp16 conversion (8 elems/thread)
// ---------------------------------------------------------------------------
__global__ __launch_bounds__(256)
void conv_f16(const float* __restrict__ s, _Float16* __restrict__ d, int n8) {
    int i = blockIdx.x * 256 + threadIdx.x;
    if (i < n8) {
        int base = i * 8;
        float4 v0 = *(const float4*)&s[base];
        float4 v1 = *(const float4*)&s[base + 4];
        half8 h;
        h[0] = (_Float16)v0.x; h[1] = (_Float16)v0.y;
        h[2] = (_Float16)v0.z; h[3] = (_Float16)v0.w;
        h[4] = (_Float16)v1.x; h[5] = (_Float16)v1.y;
        h[6] = (_Float16)v1.z; h[7] = (_Float16)v1.w;
        *(half8*)&d[base] = h;
    }
}

// ---------------------------------------------------------------------------
// MFMA projection GEMM (layer 0 only now): Cw[t][b][n] = sum_k A[m][k]*W[n][k]
// ---------------------------------------------------------------------------
__global__ __launch_bounds__(256)
void proj_gemm_f16(const _Float16* __restrict__ A, const _Float16* __restrict__ W,
                   _Float16* __restrict__ Cw, int K) {
    const int tid = threadIdx.x;
    const int wv = tid >> 6;
    const int l  = tid & 63;
    const int m0 = blockIdx.x * 128 + (wv >> 1) * 64;
    const int n0 = blockIdx.y * 128 + (wv & 1) * 64;
    const int fr = l & 15;
    const int kg = l >> 4;

    f32x4 acc[4][4];
    #pragma unroll
    for (int i = 0; i < 4; ++i)
        #pragma unroll
        for (int j = 0; j < 4; ++j) acc[i][j] = (f32x4){0.f, 0.f, 0.f, 0.f};

    const int nkc = K >> 5;
    #pragma unroll 2
    for (int kc = 0; kc < nkc; ++kc) {
        int k = kc * 32 + kg * 8;
        half8 af[4], bf[4];
        #pragma unroll
        for (int i = 0; i < 4; ++i)
            af[i] = *(const half8*)&A[(size_t)(m0 + i * 16 + fr) * K + k];
        #pragma unroll
        for (int j = 0; j < 4; ++j)
            bf[j] = *(const half8*)&W[(size_t)(n0 + j * 16 + fr) * K + k];
        #pragma unroll
        for (int i = 0; i < 4; ++i)
            #pragma unroll
            for (int j = 0; j < 4; ++j)
                acc[i][j] = __builtin_amdgcn_mfma_f32_16x16x32_f16(
                    af[i], bf[j], acc[i][j], 0, 0, 0);
    }

    #pragma unroll
    for (int i = 0; i < 4; ++i) {
        #pragma unroll
        for (int r = 0; r < 4; ++r) {
            int m = m0 + i * 16 + (l >> 4) * 4 + r;
            int t = m & (TLEN - 1);
            int b = m >> 9;
            _Float16* dst = &Cw[((size_t)t * BATCH + b) * G2];
            #pragma unroll
            for (int j = 0; j < 4; ++j)
                dst[n0 + j * 16 + (l & 15)] = (_Float16)acc[i][j][r];
        }
    }
}

// ---------------------------------------------------------------------------
// Agent-scope (device-coherent) helpers: sc0 sc1, bypass L1/per-XCD L2.
// ---------------------------------------------------------------------------
__device__ __forceinline__ void st_flag(int* p, int v) {
    __hip_atomic_store(p, v, __ATOMIC_RELAXED, __HIP_MEMORY_SCOPE_AGENT);
}
__device__ __forceinline__ int ld_flag(const int* p) {
    return __hip_atomic_load(p, __ATOMIC_RELAXED, __HIP_MEMORY_SCOPE_AGENT);
}
__device__ __forceinline__ unsigned long long ld_h2u(const unsigned short* p) {
    return __hip_atomic_load((const unsigned long long*)p, __ATOMIC_RELAXED,
                             __HIP_MEMORY_SCOPE_AGENT);
}
__device__ __forceinline__ void st_h32(unsigned int* p, unsigned int v) {
    __hip_atomic_store(p, v, __ATOMIC_RELAXED, __HIP_MEMORY_SCOPE_AGENT);
}

#define NWGL 128     // WGs per layer (fused grid = 256)
#define FSTRIDE 16   // flags 64 B apart

__global__ void rec_init(unsigned short* h0, unsigned short* h1, int* flags) {
    int i = blockIdx.x * 256 + threadIdx.x;
    if (i < BHID) { h0[i] = 0; h1[i] = 0; }          // fp16 +0.0, ring slot 0
    if (i < 2 * NWGL * FSTRIDE) flags[i] = 0;        // flags0 || flags1
}

// ---------------------------------------------------------------------------
// FUSED two-layer pipelined recurrence (lag 1).
// Blocks 0..127 = LAYER 0 (R20's verified partition: bt0=wg&3 -> 4 sync
// groups x 32 WGs; WG owns 32 j x 8 batches; JT=32 via 4 M-tiles/wave;
// red pad 21 fixes R20's row-offset bank conflict). Publishes h0-ring AND
// act0(t) (full-history fp16, no WAR) before its barrier-C drain + flag
// (flag posted EVERY t so layer 1 can consume t=511).
// Blocks 128..255 = LAYER 1: bt1=wg1&1 -> 2 sync groups x 64 WGs; WG owns
// 16 j x 16 batches. Projection ABSORBED: concat GEMM [W1|U1]x[act0(t);
// h1(t-1)], K=2048 -- waves 0-3 do the W1/act0 half, waves 4-7 the U1/h1
// half (16 MFMA/wave, A-frags 64 VGPR). Polls: wave0 -> own group flags1
// >= t; wave1 -> the two corresponding layer-0 groups' flags0 >= t+1.
// Acyclic dependency (L0 never waits on L1) => deadlock-free.
// All sync pieces are R17's proven mechanisms (poll + s_barrier, barrier B
// syncthreads, h-publish + barrier-C drain + per-WG flag, 3-ring).
// ---------------------------------------------------------------------------
__global__ __launch_bounds__(512, 1)
void ligru_fused(const _Float16* __restrict__ w16,   // [T][B][2H] fp16 (L0)
                 const _Float16* __restrict__ U0w,   // [2H][H] fp16
                 const _Float16* __restrict__ W1w,   // [2H][H] fp16
                 const _Float16* __restrict__ U1w,   // [2H][H] fp16
                 unsigned short* __restrict__ h0ring,// [3][B][H] fp16
                 unsigned short* __restrict__ h1ring,// [3][B][H] fp16
                 _Float16* __restrict__ act,         // [B][T][H] fp16 (L0 out)
                 int* __restrict__ flags0,           // NWGL flag stripes
                 int* __restrict__ flags1,           // NWGL flag stripes
                 float* __restrict__ out32,          // [B][T][H] fp32 (L1 out)
                 float* __restrict__ hlast0,         // [B][H] fp32
                 float* __restrict__ hlast1) {       // [B][H] fp32
    __shared__ float red[8][64][21];                 // 43 KB, shared by both

    const int bid = blockIdx.x;
    const int tid = threadIdx.x;
    const int wv  = tid >> 6;
    const int l   = tid & 63;
    const int mrow = l & 15;
    const int kg   = l >> 4;

    if (bid < NWGL) {
        // ================= LAYER 0 (R20 partition, pad-21) =================
        const int wg  = bid;
        const int bt  = wg & 3;
        const int jb  = wg >> 2;          // 0..31
        const int j0  = jb * 32;
        const int bg0 = bt * 8;
        const int bcol = bg0 + (l & 7);

        half8 Aa0[4], Aa1[4], Az0[4], Az1[4];
        #pragma unroll
        for (int kc = 0; kc < 4; ++kc) {
            int k0 = (wv * 4 + kc) * 32 + kg * 8;
            Aa0[kc] = *(const half8*)&U0w[(size_t)(j0 + mrow) * HID + k0];
            Aa1[kc] = *(const half8*)&U0w[(size_t)(j0 + 16 + mrow) * HID + k0];
            Az0[kc] = *(const half8*)&U0w[(size_t)(HID + j0 + mrow) * HID + k0];
            Az1[kc] = *(const half8*)&U0w[(size_t)(HID + j0 + 16 + mrow) * HID + k0];
        }

        unsigned short* h_t = h0ring;
        unsigned short* h_n = h0ring + BHID;
        unsigned short* h_p = h0ring + 2 * BHID;

        const int jl = tid & 31;          // gate row 0..31
        const int bl = tid >> 5;          // gate batch 0..7 (tid<256)
        const int bg = bg0 + (bl & 7);
        float hprev = 0.f;

        for (int t = 0; t < TLEN; ++t) {
            float wa = 0.f, wz = 0.f;
            if (tid < 256) {
                const _Float16* wt = &w16[((size_t)t * BATCH + bg) * G2];
                wa = (float)wt[j0 + jl];
                wz = (float)wt[HID + j0 + jl];
            }

            if (t > 0) {
                if (tid < 32) {
                    const int* fp = &flags0[((tid << 2) + bt) * FSTRIDE];
                    while (ld_flag(fp) < t)
                        __builtin_amdgcn_s_sleep(1);
                }
                __builtin_amdgcn_s_barrier();
            }

            f32x4 ca0 = {0,0,0,0}, ca1 = {0,0,0,0};
            f32x4 cz0 = {0,0,0,0}, cz1 = {0,0,0,0};
            #pragma unroll
            for (int kc = 0; kc < 4; ++kc) {
                int k0 = (wv * 4 + kc) * 32 + kg * 8;
                const unsigned short* hp = &h_t[(size_t)bcol * HID + k0];
                union { unsigned long long u[2]; half8 h; } B;
                B.u[0] = ld_h2u(hp);
                B.u[1] = ld_h2u(hp + 4);
                ca0 = __builtin_amdgcn_mfma_f32_16x16x32_f16(Aa0[kc], B.h, ca0, 0, 0, 0);
                ca1 = __builtin_amdgcn_mfma_f32_16x16x32_f16(Aa1[kc], B.h, ca1, 0, 0, 0);
                cz0 = __builtin_amdgcn_mfma_f32_16x16x32_f16(Az0[kc], B.h, cz0, 0, 0, 0);
                cz1 = __builtin_amdgcn_mfma_f32_16x16x32_f16(Az1[kc], B.h, cz1, 0, 0, 0);
            }
            #pragma unroll
            for (int r = 0; r < 4; ++r) {
                red[wv][kg * 4 + r][l & 15]      = ca0[r];
                red[wv][16 + kg * 4 + r][l & 15] = ca1[r];
                red[wv][32 + kg * 4 + r][l & 15] = cz0[r];
                red[wv][48 + kg * 4 + r][l & 15] = cz1[r];
            }
            __syncthreads();   // barrier B

            if (tid < 256) {
                float sa = 0.f, sz = 0.f;
                #pragma unroll
                for (int v = 0; v < 8; ++v) {
                    sa += red[v][jl][bl];
                    sz += red[v][32 + jl][bl];
                }
                float zt = fast_sigmoid(wz + sz);
                float hc = fast_tanh(wa + sa);
                float hnew = zt * hprev + (1.f - zt) * hc;
                hprev = hnew;

                unsigned short h16 =
                    __builtin_bit_cast(unsigned short, (_Float16)hnew);
                unsigned int other = __shfl_xor((unsigned int)h16, 1);
                unsigned int pk = ((jl & 1) == 0)
                    ? ((unsigned int)h16 | (other << 16))
                    : ((other) | ((unsigned int)h16 << 16));

                if (t < TLEN - 1) {
                    if ((jl & 1) == 0)
                        st_h32((unsigned int*)&h_n[(size_t)bg * HID + j0 + jl], pk);
                } else {
                    hlast0[(size_t)bg * HID + j0 + jl] = hnew;
                }
                // act0(t) publish (coherent, inside the pre-flag drain)
                if ((jl & 1) == 0)
                    st_h32((unsigned int*)&act[((size_t)bg * TLEN + t) * HID
                                               + j0 + jl], pk);
            }

            __syncthreads();   // barrier C: drain h + act stores to LLC
            if (tid == 0) st_flag(&flags0[wg * FSTRIDE], t + 1);  // every t

            unsigned short* tmp = h_t; h_t = h_n; h_n = h_p; h_p = tmp;
        }
    } else {
        // ================= LAYER 1 (concat K=2048, lag 1) =================
        const int wg1 = bid - NWGL;
        const int bt1 = wg1 & 1;
        const int jb1 = wg1 >> 1;         // 0..63
        const int j1  = jb1 * 16;
        const int bg1 = bt1 * 16;
        const int bcol = bg1 + (l & 15);  // 16 real batch cols

        // A-frags: waves 0-3 = W1 (act half), waves 4-7 = U1 (h half)
        const _Float16* Abase = (wv < 4) ? W1w : U1w;
        const int kb = (wv & 3) * 256;
        half8 Aa[8], Az[8];
        #pragma unroll
        for (int kc = 0; kc < 8; ++kc) {
            int k0 = kb + kc * 32 + kg * 8;
            Aa[kc] = *(const half8*)&Abase[(size_t)(j1 + mrow) * HID + k0];
            Az[kc] = *(const half8*)&Abase[(size_t)(HID + j1 + mrow) * HID + k0];
        }

        unsigned short* h_t = h1ring;
        unsigned short* h_n = h1ring + BHID;
        unsigned short* h_p = h1ring + 2 * BHID;

        const int jl = tid & 15;          // gate row 0..15
        const int bl = (tid >> 4) & 15;   // gate batch 0..15 (tid<256)
        const int bg = bg1 + bl;
        float hprev = 0.f;

        for (int t = 0; t < TLEN; ++t) {
            // polls: wave 0 -> own group h1(t); wave 1 -> layer-0 act(t)
            if (wv == 0 && t > 0) {
                const int* fp = &flags1[((l << 1) + bt1) * FSTRIDE];
                while (ld_flag(fp) < t)
                    __builtin_amdgcn_s_sleep(1);
            }
            if (wv == 1) {
                // layer-0 groups {2*bt1, 2*bt1+1}: wg0 = (jb0<<2)+bt0
                const int* fp = &flags0[(((l >> 1) << 2) + 2 * bt1 + (l & 1))
                                        * FSTRIDE];
                while (ld_flag(fp) < t + 1)
                    __builtin_amdgcn_s_sleep(1);
            }
            __builtin_amdgcn_s_barrier();

            // B frags: act0(t) for waves 0-3, h1(t-1) for waves 4-7
            const unsigned short* bsrc = (wv < 4)
                ? (const unsigned short*)act + ((size_t)bcol * TLEN + t) * HID + kb
                : h_t + (size_t)bcol * HID + kb;

            f32x4 ca = {0,0,0,0}, cz = {0,0,0,0};
            #pragma unroll
            for (int kc = 0; kc < 8; ++kc) {
                const unsigned short* hp = bsrc + kc * 32 + kg * 8;
                union { unsigned long long u[2]; half8 h; } B;
                B.u[0] = ld_h2u(hp);
                B.u[1] = ld_h2u(hp + 4);
                ca = __builtin_amdgcn_mfma_f32_16x16x32_f16(Aa[kc], B.h, ca, 0, 0, 0);
                cz = __builtin_amdgcn_mfma_f32_16x16x32_f16(Az[kc], B.h, cz, 0, 0, 0);
            }
            #pragma unroll
            for (int r = 0; r < 4; ++r) {
                red[wv][kg * 4 + r][l & 15]      = ca[r];
                red[wv][16 + kg * 4 + r][l & 15] = cz[r];
            }
            __syncthreads();   // barrier B

            unsigned int pk = 0;
            float hnew = 0.f;
            if (tid < 256) {
                float sa = 0.f, sz = 0.f;
                #pragma unroll
                for (int v = 0; v < 8; ++v) {
                    sa += red[v][jl][bl];
                    sz += red[v][16 + jl][bl];
                }
                float zt = fast_sigmoid(sz);
                float hc = fast_tanh(sa);
                hnew = zt * hprev + (1.f - zt) * hc;
                hprev = hnew;

                unsigned short h16 =
                    __builtin_bit_cast(unsigned short, (_Float16)hnew);
                unsigned int other = __shfl_xor((unsigned int)h16, 1);
                pk = ((jl & 1) == 0)
                    ? ((unsigned int)h16 | (other << 16))
                    : ((other) | ((unsigned int)h16 << 16));

                if (t < TLEN - 1) {
                    if ((jl & 1) == 0)
                        st_h32((unsigned int*)&h_n[(size_t)bg * HID + j1 + jl], pk);
                } else {
                    hlast1[(size_t)bg * HID + j1 + jl] = hnew;
                }
            }

            if (t < TLEN - 1) {
                __syncthreads();   // barrier C: drain h1 stores
                if (tid == 0) st_flag(&flags1[wg1 * FSTRIDE], t + 1);
            }
            // final output store, deferred off the critical path
            if (tid < 256)
                out32[((size_t)bg * TLEN + t) * HID + j1 + jl] = hnew;

            unsigned short* tmp = h_t; h_t = h_n; h_n = h_p; h_p = tmp;
        }
    }
}

// ---------------------------------------------------------------------------
extern "C" void kernel_launch(void* const* d_in, const int* in_sizes, int n_in,
                              void* d_out, int out_size, void* d_ws, size_t ws_size,
                              hipStream_t stream) {
    (void)in_sizes; (void)n_in; (void)out_size; (void)ws_size;

    const float* x  = (const float*)d_in[0];
    const float* W0 = (const float*)d_in[1];
    const float* U0 = (const float*)d_in[2];
    const float* W1 = (const float*)d_in[3];
    const float* U1 = (const float*)d_in[4];

    float* out    = (float*)d_out;                              // [B,T,H]
    float* hstack = out + (size_t)BATCH * TLEN * HID;           // [2,B,H]

    // workspace layout (~126 MB)
    int*            flags0 = (int*)d_ws;                              // 8 KB
    int*            flags1 = flags0 + NWGL * FSTRIDE;                 // 8 KB
    unsigned short* h0ring = (unsigned short*)(flags1 + NWGL * FSTRIDE); // 192 KB
    unsigned short* h1ring = h0ring + 3 * BHID;                       // 192 KB
    _Float16*       W016   = (_Float16*)(h1ring + 3 * BHID);          // 2 MB
    _Float16*       U016   = W016 + (size_t)G2 * 512;                 // 4 MB
    _Float16*       W116   = U016 + (size_t)G2 * HID;                 // 4 MB
    _Float16*       U116   = W116 + (size_t)G2 * HID;                 // 4 MB
    _Float16*       x16    = U116 + (size_t)G2 * HID;                 // 16 MB
    _Float16*       act    = x16 + (size_t)BATCH * TLEN * 512;        // 32 MB
    _Float16*       wbuf   = act + (size_t)BATCH * TLEN * HID;        // 64 MB

    dim3 gg(16384 / 128, 2048 / 128);
    int init_blocks = (BHID + 255) / 256;

    // ---- pre-work: conversions + layer-0 projection ----
    conv_f16<<<(BATCH * TLEN * 512 / 8 + 255) / 256, 256, 0, stream>>>(
        x, x16, BATCH * TLEN * 512 / 8);
    conv_f16<<<(G2 * 512 / 8 + 255) / 256, 256, 0, stream>>>(
        W0, W016, G2 * 512 / 8);
    conv_f16<<<(G2 * HID / 8 + 255) / 256, 256, 0, stream>>>(
        U0, U016, G2 * HID / 8);
    conv_f16<<<(G2 * HID / 8 + 255) / 256, 256, 0, stream>>>(
        W1, W116, G2 * HID / 8);
    conv_f16<<<(G2 * HID / 8 + 255) / 256, 256, 0, stream>>>(
        U1, U116, G2 * HID / 8);
    proj_gemm_f16<<<gg, 256, 0, stream>>>(x16, W016, wbuf, 512);
    rec_init<<<init_blocks, 256, 0, stream>>>(h0ring, h1ring, flags0);

    // ---- fused pipelined recurrence: both layers, lag 1 ----
    ligru_fused<<<dim3(2 * NWGL), dim3(512), 0, stream>>>(
        wbuf, U016, W116, U116, h0ring, h1ring, act, flags0, flags1,
        out, hstack, hstack + BHID);
}

// Round 22
// 1966.991 us; speedup vs baseline: 1.8906x; 1.4224x over previous
//
#include <hip/hip_runtime.h>
#include <math.h>

#define BATCH 32
#define TLEN  512
#define HID   1024
#define G2    2048   // 2*H
#define BHID (BATCH * HID)

typedef _Float16 half8 __attribute__((ext_vector_type(8)));
typedef float f32x4 __attribute__((ext_vector_type(4)));

#define LOG2E 1.44269504f
__device__ __forceinline__ float fast_sigmoid(float z) {
    return __builtin_amdgcn_rcpf(1.f + __builtin_amdgcn_exp2f(-LOG2E * z));
}
__device__ __forceinline__ float fast_tanh(float a) {
    return 1.f - 2.f * __builtin_amdgcn_rcpf(
        1.f + __builtin_amdgcn_exp2f(2.f * LOG2E * a));
}

// ---------------------------------------------------------------------------
// Batched 16B coherent loads (sc0 sc1 = bypass L1/L2, read LLC -- same
// semantics as __hip_atomic_load AGENT, half the request count). All loads
// issued before one vmcnt(0): latency stays pipelined (NOT per-load waits).
// kc stride = 32 halves = 64 B -> compile-time offsets.
// ---------------------------------------------------------------------------
__device__ __forceinline__ void ld_b16x4(const unsigned short* p,
                                         half8& b0, half8& b1,
                                         half8& b2, half8& b3) {
    asm volatile(
        "global_load_dwordx4 %0, %4, off sc0 sc1\n\t"
        "global_load_dwordx4 %1, %4, off offset:64 sc0 sc1\n\t"
        "global_load_dwordx4 %2, %4, off offset:128 sc0 sc1\n\t"
        "global_load_dwordx4 %3, %4, off offset:192 sc0 sc1\n\t"
        "s_waitcnt vmcnt(0)"
        : "=&v"(b0), "=&v"(b1), "=&v"(b2), "=&v"(b3)
        : "v"(p) : "memory");
}
__device__ __forceinline__ void ld_b16x8(const unsigned short* p,
                                         half8& b0, half8& b1, half8& b2,
                                         half8& b3, half8& b4, half8& b5,
                                         half8& b6, half8& b7) {
    asm volatile(
        "global_load_dwordx4 %0, %8, off sc0 sc1\n\t"
        "global_load_dwordx4 %1, %8, off offset:64 sc0 sc1\n\t"
        "global_load_dwordx4 %2, %8, off offset:128 sc0 sc1\n\t"
        "global_load_dwordx4 %3, %8, off offset:192 sc0 sc1\n\t"
        "global_load_dwordx4 %4, %8, off offset:256 sc0 sc1\n\t"
        "global_load_dwordx4 %5, %8, off offset:320 sc0 sc1\n\t"
        "global_load_dwordx4 %6, %8, off offset:384 sc0 sc1\n\t"
        "global_load_dwordx4 %7, %8, off offset:448 sc0 sc1\n\t"
        "s_waitcnt vmcnt(0)"
        : "=&v"(b0), "=&v"(b1), "=&v"(b2), "=&v"(b3),
          "=&v"(b4), "=&v"(b5), "=&v"(b6), "=&v"(b7)
        : "v"(p) : "memory");
}

// ---------------------------------------------------------------------------
// fp32 -> fp16 conversion (8 elems/thread)
// ---------------------------------------------------------------------------
__global__ __launch_bounds__(256)
void conv_f16(const float* __restrict__ s, _Float16* __restrict__ d, int n8) {
    int i = blockIdx.x * 256 + threadIdx.x;
    if (i < n8) {
        int base = i * 8;
        float4 v0 = *(const float4*)&s[base];
        float4 v1 = *(const float4*)&s[base + 4];
        half8 h;
        h[0] = (_Float16)v0.x; h[1] = (_Float16)v0.y;
        h[2] = (_Float16)v0.z; h[3] = (_Float16)v0.w;
        h[4] = (_Float16)v1.x; h[5] = (_Float16)v1.y;
        h[6] = (_Float16)v1.z; h[7] = (_Float16)v1.w;
        *(half8*)&d[base] = h;
    }
}

// ---------------------------------------------------------------------------
// MFMA projection GEMM (layer 0 only): Cw[t][b][n] = sum_k A[m][k]*W[n][k]
// ---------------------------------------------------------------------------
__global__ __launch_bounds__(256)
void proj_gemm_f16(const _Float16* __restrict__ A, const _Float16* __restrict__ W,
                   _Float16* __restrict__ Cw, int K) {
    const int tid = threadIdx.x;
    const int wv = tid >> 6;
    const int l  = tid & 63;
    const int m0 = blockIdx.x * 128 + (wv >> 1) * 64;
    const int n0 = blockIdx.y * 128 + (wv & 1) * 64;
    const int fr = l & 15;
    const int kg = l >> 4;

    f32x4 acc[4][4];
    #pragma unroll
    for (int i = 0; i < 4; ++i)
        #pragma unroll
        for (int j = 0; j < 4; ++j) acc[i][j] = (f32x4){0.f, 0.f, 0.f, 0.f};

    const int nkc = K >> 5;
    #pragma unroll 2
    for (int kc = 0; kc < nkc; ++kc) {
        int k = kc * 32 + kg * 8;
        half8 af[4], bf[4];
        #pragma unroll
        for (int i = 0; i < 4; ++i)
            af[i] = *(const half8*)&A[(size_t)(m0 + i * 16 + fr) * K + k];
        #pragma unroll
        for (int j = 0; j < 4; ++j)
            bf[j] = *(const half8*)&W[(size_t)(n0 + j * 16 + fr) * K + k];
        #pragma unroll
        for (int i = 0; i < 4; ++i)
            #pragma unroll
            for (int j = 0; j < 4; ++j)
                acc[i][j] = __builtin_amdgcn_mfma_f32_16x16x32_f16(
                    af[i], bf[j], acc[i][j], 0, 0, 0);
    }

    #pragma unroll
    for (int i = 0; i < 4; ++i) {
        #pragma unroll
        for (int r = 0; r < 4; ++r) {
            int m = m0 + i * 16 + (l >> 4) * 4 + r;
            int t = m & (TLEN - 1);
            int b = m >> 9;
            _Float16* dst = &Cw[((size_t)t * BATCH + b) * G2];
            #pragma unroll
            for (int j = 0; j < 4; ++j)
                dst[n0 + j * 16 + (l & 15)] = (_Float16)acc[i][j][r];
        }
    }
}

// ---------------------------------------------------------------------------
// Agent-scope (device-coherent) helpers.
// ---------------------------------------------------------------------------
__device__ __forceinline__ void st_flag(int* p, int v) {
    __hip_atomic_store(p, v, __ATOMIC_RELAXED, __HIP_MEMORY_SCOPE_AGENT);
}
__device__ __forceinline__ int ld_flag(const int* p) {
    return __hip_atomic_load(p, __ATOMIC_RELAXED, __HIP_MEMORY_SCOPE_AGENT);
}
__device__ __forceinline__ void st_h32(unsigned int* p, unsigned int v) {
    __hip_atomic_store(p, v, __ATOMIC_RELAXED, __HIP_MEMORY_SCOPE_AGENT);
}

#define NWGL 128     // WGs per layer (fused grid = 256)
#define FSTRIDE 16   // flags 64 B apart

__global__ void rec_init(unsigned short* h0, unsigned short* h1, int* flags) {
    int i = blockIdx.x * 256 + threadIdx.x;
    if (i < BHID) { h0[i] = 0; h1[i] = 0; }
    if (i < 2 * NWGL * FSTRIDE) flags[i] = 0;
}

// ---------------------------------------------------------------------------
// FUSED two-layer pipelined recurrence (lag 1) -- R21 structure verbatim,
// with B-fragment loads widened to batched 16B coherent loads (R22 delta).
// Blocks 0..127 = LAYER 0 (4 sync groups x 32 WGs, 32j x 8b, 4 M-tiles/wave,
// red pad 21). Blocks 128..255 = LAYER 1 (2 groups x 64 WGs, 16j x 16b,
// concat K=2048: waves 0-3 W1/act0(t), waves 4-7 U1/h1(t-1)).
// Sync: R17 mechanisms; L1 wave1 polls L0 flags >= t+1. Acyclic.
// ---------------------------------------------------------------------------
__global__ __launch_bounds__(512, 1)
void ligru_fused(const _Float16* __restrict__ w16,   // [T][B][2H] fp16 (L0)
                 const _Float16* __restrict__ U0w,   // [2H][H] fp16
                 const _Float16* __restrict__ W1w,   // [2H][H] fp16
                 const _Float16* __restrict__ U1w,   // [2H][H] fp16
                 unsigned short* __restrict__ h0ring,// [3][B][H] fp16
                 unsigned short* __restrict__ h1ring,// [3][B][H] fp16
                 _Float16* __restrict__ act,         // [B][T][H] fp16 (L0 out)
                 int* __restrict__ flags0,           // NWGL flag stripes
                 int* __restrict__ flags1,           // NWGL flag stripes
                 float* __restrict__ out32,          // [B][T][H] fp32 (L1 out)
                 float* __restrict__ hlast0,         // [B][H] fp32
                 float* __restrict__ hlast1) {       // [B][H] fp32
    __shared__ float red[8][64][21];                 // 43 KB, shared by both

    const int bid = blockIdx.x;
    const int tid = threadIdx.x;
    const int wv  = tid >> 6;
    const int l   = tid & 63;
    const int mrow = l & 15;
    const int kg   = l >> 4;

    if (bid < NWGL) {
        // ================= LAYER 0 =================
        const int wg  = bid;
        const int bt  = wg & 3;
        const int jb  = wg >> 2;          // 0..31
        const int j0  = jb * 32;
        const int bg0 = bt * 8;
        const int bcol = bg0 + (l & 7);

        half8 Aa0[4], Aa1[4], Az0[4], Az1[4];
        #pragma unroll
        for (int kc = 0; kc < 4; ++kc) {
            int k0 = (wv * 4 + kc) * 32 + kg * 8;
            Aa0[kc] = *(const half8*)&U0w[(size_t)(j0 + mrow) * HID + k0];
            Aa1[kc] = *(const half8*)&U0w[(size_t)(j0 + 16 + mrow) * HID + k0];
            Az0[kc] = *(const half8*)&U0w[(size_t)(HID + j0 + mrow) * HID + k0];
            Az1[kc] = *(const half8*)&U0w[(size_t)(HID + j0 + 16 + mrow) * HID + k0];
        }

        unsigned short* h_t = h0ring;
        unsigned short* h_n = h0ring + BHID;
        unsigned short* h_p = h0ring + 2 * BHID;

        const int jl = tid & 31;
        const int bl = tid >> 5;          // 0..7 for tid<256
        const int bg = bg0 + (bl & 7);
        float hprev = 0.f;

        for (int t = 0; t < TLEN; ++t) {
            float wa = 0.f, wz = 0.f;
            if (tid < 256) {
                const _Float16* wt = &w16[((size_t)t * BATCH + bg) * G2];
                wa = (float)wt[j0 + jl];
                wz = (float)wt[HID + j0 + jl];
            }

            if (t > 0) {
                if (tid < 32) {
                    const int* fp = &flags0[((tid << 2) + bt) * FSTRIDE];
                    while (ld_flag(fp) < t)
                        __builtin_amdgcn_s_sleep(1);
                }
                __builtin_amdgcn_s_barrier();
            }

            // B frags: one batched 4x16B coherent load (kc stride 64 B)
            half8 B0, B1, B2, B3;
            ld_b16x4(&h_t[(size_t)bcol * HID + wv * 128 + kg * 8],
                     B0, B1, B2, B3);

            f32x4 ca0 = {0,0,0,0}, ca1 = {0,0,0,0};
            f32x4 cz0 = {0,0,0,0}, cz1 = {0,0,0,0};
            ca0 = __builtin_amdgcn_mfma_f32_16x16x32_f16(Aa0[0], B0, ca0, 0, 0, 0);
            ca1 = __builtin_amdgcn_mfma_f32_16x16x32_f16(Aa1[0], B0, ca1, 0, 0, 0);
            cz0 = __builtin_amdgcn_mfma_f32_16x16x32_f16(Az0[0], B0, cz0, 0, 0, 0);
            cz1 = __builtin_amdgcn_mfma_f32_16x16x32_f16(Az1[0], B0, cz1, 0, 0, 0);
            ca0 = __builtin_amdgcn_mfma_f32_16x16x32_f16(Aa0[1], B1, ca0, 0, 0, 0);
            ca1 = __builtin_amdgcn_mfma_f32_16x16x32_f16(Aa1[1], B1, ca1, 0, 0, 0);
            cz0 = __builtin_amdgcn_mfma_f32_16x16x32_f16(Az0[1], B1, cz0, 0, 0, 0);
            cz1 = __builtin_amdgcn_mfma_f32_16x16x32_f16(Az1[1], B1, cz1, 0, 0, 0);
            ca0 = __builtin_amdgcn_mfma_f32_16x16x32_f16(Aa0[2], B2, ca0, 0, 0, 0);
            ca1 = __builtin_amdgcn_mfma_f32_16x16x32_f16(Aa1[2], B2, ca1, 0, 0, 0);
            cz0 = __builtin_amdgcn_mfma_f32_16x16x32_f16(Az0[2], B2, cz0, 0, 0, 0);
            cz1 = __builtin_amdgcn_mfma_f32_16x16x32_f16(Az1[2], B2, cz1, 0, 0, 0);
            ca0 = __builtin_amdgcn_mfma_f32_16x16x32_f16(Aa0[3], B3, ca0, 0, 0, 0);
            ca1 = __builtin_amdgcn_mfma_f32_16x16x32_f16(Aa1[3], B3, ca1, 0, 0, 0);
            cz0 = __builtin_amdgcn_mfma_f32_16x16x32_f16(Az0[3], B3, cz0, 0, 0, 0);
            cz1 = __builtin_amdgcn_mfma_f32_16x16x32_f16(Az1[3], B3, cz1, 0, 0, 0);

            #pragma unroll
            for (int r = 0; r < 4; ++r) {
                red[wv][kg * 4 + r][l & 15]      = ca0[r];
                red[wv][16 + kg * 4 + r][l & 15] = ca1[r];
                red[wv][32 + kg * 4 + r][l & 15] = cz0[r];
                red[wv][48 + kg * 4 + r][l & 15] = cz1[r];
            }
            __syncthreads();   // barrier B

            if (tid < 256) {
                float sa = 0.f, sz = 0.f;
                #pragma unroll
                for (int v = 0; v < 8; ++v) {
                    sa += red[v][jl][bl];
                    sz += red[v][32 + jl][bl];
                }
                float zt = fast_sigmoid(wz + sz);
                float hc = fast_tanh(wa + sa);
                float hnew = zt * hprev + (1.f - zt) * hc;
                hprev = hnew;

                unsigned short h16 =
                    __builtin_bit_cast(unsigned short, (_Float16)hnew);
                unsigned int other = __shfl_xor((unsigned int)h16, 1);
                unsigned int pk = ((jl & 1) == 0)
                    ? ((unsigned int)h16 | (other << 16))
                    : ((other) | ((unsigned int)h16 << 16));

                if (t < TLEN - 1) {
                    if ((jl & 1) == 0)
                        st_h32((unsigned int*)&h_n[(size_t)bg * HID + j0 + jl], pk);
                } else {
                    hlast0[(size_t)bg * HID + j0 + jl] = hnew;
                }
                if ((jl & 1) == 0)
                    st_h32((unsigned int*)&act[((size_t)bg * TLEN + t) * HID
                                               + j0 + jl], pk);
            }

            __syncthreads();   // barrier C: drain h + act stores to LLC
            if (tid == 0) st_flag(&flags0[wg * FSTRIDE], t + 1);

            unsigned short* tmp = h_t; h_t = h_n; h_n = h_p; h_p = tmp;
        }
    } else {
        // ================= LAYER 1 (concat K=2048, lag 1) =================
        const int wg1 = bid - NWGL;
        const int bt1 = wg1 & 1;
        const int jb1 = wg1 >> 1;         // 0..63
        const int j1  = jb1 * 16;
        const int bg1 = bt1 * 16;
        const int bcol = bg1 + (l & 15);

        const _Float16* Abase = (wv < 4) ? W1w : U1w;
        const int kb = (wv & 3) * 256;
        half8 Aa[8], Az[8];
        #pragma unroll
        for (int kc = 0; kc < 8; ++kc) {
            int k0 = kb + kc * 32 + kg * 8;
            Aa[kc] = *(const half8*)&Abase[(size_t)(j1 + mrow) * HID + k0];
            Az[kc] = *(const half8*)&Abase[(size_t)(HID + j1 + mrow) * HID + k0];
        }

        unsigned short* h_t = h1ring;
        unsigned short* h_n = h1ring + BHID;
        unsigned short* h_p = h1ring + 2 * BHID;

        const int jl = tid & 15;
        const int bl = (tid >> 4) & 15;
        const int bg = bg1 + bl;
        float hprev = 0.f;

        for (int t = 0; t < TLEN; ++t) {
            if (wv == 0 && t > 0) {
                const int* fp = &flags1[((l << 1) + bt1) * FSTRIDE];
                while (ld_flag(fp) < t)
                    __builtin_amdgcn_s_sleep(1);
            }
            if (wv == 1) {
                const int* fp = &flags0[(((l >> 1) << 2) + 2 * bt1 + (l & 1))
                                        * FSTRIDE];
                while (ld_flag(fp) < t + 1)
                    __builtin_amdgcn_s_sleep(1);
            }
            __builtin_amdgcn_s_barrier();

            const unsigned short* bsrc = (wv < 4)
                ? (const unsigned short*)act + ((size_t)bcol * TLEN + t) * HID
                  + kb + kg * 8
                : h_t + (size_t)bcol * HID + kb + kg * 8;

            // B frags: one batched 8x16B coherent load (kc stride 64 B)
            half8 B0, B1, B2, B3, B4, B5, B6, B7;
            ld_b16x8(bsrc, B0, B1, B2, B3, B4, B5, B6, B7);

            f32x4 ca = {0,0,0,0}, cz = {0,0,0,0};
            ca = __builtin_amdgcn_mfma_f32_16x16x32_f16(Aa[0], B0, ca, 0, 0, 0);
            cz = __builtin_amdgcn_mfma_f32_16x16x32_f16(Az[0], B0, cz, 0, 0, 0);
            ca = __builtin_amdgcn_mfma_f32_16x16x32_f16(Aa[1], B1, ca, 0, 0, 0);
            cz = __builtin_amdgcn_mfma_f32_16x16x32_f16(Az[1], B1, cz, 0, 0, 0);
            ca = __builtin_amdgcn_mfma_f32_16x16x32_f16(Aa[2], B2, ca, 0, 0, 0);
            cz = __builtin_amdgcn_mfma_f32_16x16x32_f16(Az[2], B2, cz, 0, 0, 0);
            ca = __builtin_amdgcn_mfma_f32_16x16x32_f16(Aa[3], B3, ca, 0, 0, 0);
            cz = __builtin_amdgcn_mfma_f32_16x16x32_f16(Az[3], B3, cz, 0, 0, 0);
            ca = __builtin_amdgcn_mfma_f32_16x16x32_f16(Aa[4], B4, ca, 0, 0, 0);
            cz = __builtin_amdgcn_mfma_f32_16x16x32_f16(Az[4], B4, cz, 0, 0, 0);
            ca = __builtin_amdgcn_mfma_f32_16x16x32_f16(Aa[5], B5, ca, 0, 0, 0);
            cz = __builtin_amdgcn_mfma_f32_16x16x32_f16(Az[5], B5, cz, 0, 0, 0);
            ca = __builtin_amdgcn_mfma_f32_16x16x32_f16(Aa[6], B6, ca, 0, 0, 0);
            cz = __builtin_amdgcn_mfma_f32_16x16x32_f16(Az[6], B6, cz, 0, 0, 0);
            ca = __builtin_amdgcn_mfma_f32_16x16x32_f16(Aa[7], B7, ca, 0, 0, 0);
            cz = __builtin_amdgcn_mfma_f32_16x16x32_f16(Az[7], B7, cz, 0, 0, 0);

            #pragma unroll
            for (int r = 0; r < 4; ++r) {
                red[wv][kg * 4 + r][l & 15]      = ca[r];
                red[wv][16 + kg * 4 + r][l & 15] = cz[r];
            }
            __syncthreads();   // barrier B

            unsigned int pk = 0;
            float hnew = 0.f;
            if (tid < 256) {
                float sa = 0.f, sz = 0.f;
                #pragma unroll
                for (int v = 0; v < 8; ++v) {
                    sa += red[v][jl][bl];
                    sz += red[v][16 + jl][bl];
                }
                float zt = fast_sigmoid(sz);
                float hc = fast_tanh(sa);
                hnew = zt * hprev + (1.f - zt) * hc;
                hprev = hnew;

                unsigned short h16 =
                    __builtin_bit_cast(unsigned short, (_Float16)hnew);
                unsigned int other = __shfl_xor((unsigned int)h16, 1);
                pk = ((jl & 1) == 0)
                    ? ((unsigned int)h16 | (other << 16))
                    : ((other) | ((unsigned int)h16 << 16));

                if (t < TLEN - 1) {
                    if ((jl & 1) == 0)
                        st_h32((unsigned int*)&h_n[(size_t)bg * HID + j1 + jl], pk);
                } else {
                    hlast1[(size_t)bg * HID + j1 + jl] = hnew;
                }
            }

            if (t < TLEN - 1) {
                __syncthreads();   // barrier C: drain h1 stores
                if (tid == 0) st_flag(&flags1[wg1 * FSTRIDE], t + 1);
            }
            if (tid < 256)
                out32[((size_t)bg * TLEN + t) * HID + j1 + jl] = hnew;

            unsigned short* tmp = h_t; h_t = h_n; h_n = h_p; h_p = tmp;
        }
    }
}

// ---------------------------------------------------------------------------
extern "C" void kernel_launch(void* const* d_in, const int* in_sizes, int n_in,
                              void* d_out, int out_size, void* d_ws, size_t ws_size,
                              hipStream_t stream) {
    (void)in_sizes; (void)n_in; (void)out_size; (void)ws_size;

    const float* x  = (const float*)d_in[0];
    const float* W0 = (const float*)d_in[1];
    const float* U0 = (const float*)d_in[2];
    const float* W1 = (const float*)d_in[3];
    const float* U1 = (const float*)d_in[4];

    float* out    = (float*)d_out;                              // [B,T,H]
    float* hstack = out + (size_t)BATCH * TLEN * HID;           // [2,B,H]

    // workspace layout (~126 MB)
    int*            flags0 = (int*)d_ws;                              // 8 KB
    int*            flags1 = flags0 + NWGL * FSTRIDE;                 // 8 KB
    unsigned short* h0ring = (unsigned short*)(flags1 + NWGL * FSTRIDE); // 192 KB
    unsigned short* h1ring = h0ring + 3 * BHID;                       // 192 KB
    _Float16*       W016   = (_Float16*)(h1ring + 3 * BHID);          // 2 MB
    _Float16*       U016   = W016 + (size_t)G2 * 512;                 // 4 MB
    _Float16*       W116   = U016 + (size_t)G2 * HID;                 // 4 MB
    _Float16*       U116   = W116 + (size_t)G2 * HID;                 // 4 MB
    _Float16*       x16    = U116 + (size_t)G2 * HID;                 // 16 MB
    _Float16*       act    = x16 + (size_t)BATCH * TLEN * 512;        // 32 MB
    _Float16*       wbuf   = act + (size_t)BATCH * TLEN * HID;        // 64 MB

    dim3 gg(16384 / 128, 2048 / 128);
    int init_blocks = (BHID + 255) / 256;

    // ---- pre-work: conversions + layer-0 projection ----
    conv_f16<<<(BATCH * TLEN * 512 / 8 + 255) / 256, 256, 0, stream>>>(
        x, x16, BATCH * TLEN * 512 / 8);
    conv_f16<<<(G2 * 512 / 8 + 255) / 256, 256, 0, stream>>>(
        W0, W016, G2 * 512 / 8);
    conv_f16<<<(G2 * HID / 8 + 255) / 256, 256, 0, stream>>>(
        U0, U016, G2 * HID / 8);
    conv_f16<<<(G2 * HID / 8 + 255) / 256, 256, 0, stream>>>(
        W1, W116, G2 * HID / 8);
    conv_f16<<<(G2 * HID / 8 + 255) / 256, 256, 0, stream>>>(
        U1, U116, G2 * HID / 8);
    proj_gemm_f16<<<gg, 256, 0, stream>>>(x16, W016, wbuf, 512);
    rec_init<<<init_blocks, 256, 0, stream>>>(h0ring, h1ring, flags0);

    // ---- fused pipelined recurrence: both layers, lag 1 ----
    ligru_fused<<<dim3(2 * NWGL), dim3(512), 0, stream>>>(
        wbuf, U016, W116, U116, h0ring, h1ring, act, flags0, flags1,
        out, hstack, hstack + BHID);
}